// Round 9
// baseline (245.894 us; speedup 1.0000x reference)
//
#include <hip/hip_runtime.h>
#include <stdint.h>

#define M_ROWS 65536
#define C_DIM  256
#define K_CLS  20
#define P_POS  2048
#define MARGIN_F 0.3f
#define EPS_D (0.0001f / 256.0f)
#define SCALE1 0x7F7F7F7Fu   /* e8m0 127 = 2^0 in all four bytes */
#define SCALE2 0x80808080u   /* e8m0 128 = 2^1 in all four bytes (A operand) */

typedef float floatx4 __attribute__((ext_vector_type(4)));
typedef int   intx8   __attribute__((ext_vector_type(8)));
union Frag8 { intx8 v; uint4 q[2]; };

// async 16B/lane global -> LDS (wave-uniform LDS base + lane*16)
__device__ __forceinline__ void async_copy16(const void* g, void* l) {
    __builtin_amdgcn_global_load_lds(
        (const __attribute__((address_space(1))) void*)g,
        (__attribute__((address_space(3))) void*)l, 16, 0, 0);
}
__device__ __forceinline__ float sigm(float x) { return 1.f / (1.f + __expf(-x)); }

__device__ __forceinline__ void negA(Frag8& f) {
#pragma unroll
    for (int t = 0; t < 8; ++t) f.v[t] ^= (int)0x80808080u;
}
__device__ __forceinline__ unsigned int mkey(float f) {
    const uint32_t u = __float_as_uint(f);
    return (u & 0x80000000u) ? ~u : (u | 0x80000000u);
}

#define VMCNT2() asm volatile("s_waitcnt vmcnt(2)" ::: "memory")
#define VMCNT0() asm volatile("s_waitcnt vmcnt(0)" ::: "memory")

// ------- Kernel 1: sigmoid -> fp8 e4m3 table + fp8-exact row norms ----------
__global__ __launch_bounds__(256) void sigmoid_norm_k(
        const float* __restrict__ feat,
        unsigned int* __restrict__ S8,     // [M][64] uint = 256 fp8/row
        float* __restrict__ xx,
        unsigned int* __restrict__ hp,
        unsigned int* __restrict__ hn) {
    {
        const int idx = blockIdx.x * 256 + threadIdx.x;
        if (idx < K_CLS * P_POS) { hp[idx] = 0u; hn[idx] = 0xFFFFFFFFu; }
    }
    const int wave = threadIdx.x >> 6, lane = threadIdx.x & 63;
    for (int g = blockIdx.x; g < M_ROWS / 4; g += 2048) {
        const int row = g * 4 + wave;
        const float4 v = *(const float4*)(feat + (size_t)row * C_DIM + lane * 4);

        const int p01 = __builtin_amdgcn_cvt_pk_fp8_f32(sigm(v.x), sigm(v.y), 0, false);
        const int p23 = __builtin_amdgcn_cvt_pk_fp8_f32(sigm(v.z), sigm(v.w), 0, false);
        S8[(size_t)row * 64 + lane] =
            (unsigned int)(p01 & 0xFFFF) | ((unsigned int)p23 << 16);

        const float q0 = __builtin_amdgcn_cvt_f32_fp8(p01, 0);
        const float q1 = __builtin_amdgcn_cvt_f32_fp8(p01, 1);
        const float q2 = __builtin_amdgcn_cvt_f32_fp8(p23, 0);
        const float q3 = __builtin_amdgcn_cvt_f32_fp8(p23, 1);
        float sum = q0 * q0 + q1 * q1 + q2 * q2 + q3 * q3;
#pragma unroll
        for (int off = 32; off; off >>= 1) sum += __shfl_down(sum, off);
        if (lane == 0) xx[row] = sum;
    }
}

// ---------- Kernel 2: fused MX-fp8 distance-GEMM + arg-select ---------------
// R24: SYMMETRY. Cross-round invariant: select time ~ const * total tile
// count (~3400 cyc/tile) across 3 sync structures / 2 tile sizes / 2
// occupancies / 2 LDS styles. The pos-pos matrix is symmetric -> compute only
// the upper triangle of 256x256 super-tiles (36 of 64 per class) and merge
// each off-diagonal tile BOTH row-wise (hp[i], idx=j) and col-wise (hp[j],
// idx=i). Tiles: 20480 -> 16000 (78%).
// KEY CORRECTNESS POINT: mixed row/col candidates in hp[j] must compare the
// same quantity -> pos blocks encode FULL d^2 = acc + xx_i (xxL broadcast
// + fadd); value-order vs old enc(yy-2xy) is identical per row (const xx_i).
// hn (neg) path: verbatim R21 core, enc(yy-2xy).
// Core: typed-LDS Bt4 ds_read_b128, 3-ring counted vmcnt, MFMA-folded
// yy-2xy (A sign-flip fp8 + A-scale 2^1 + C=yv splat), monotone-key atomics.
// Col path merges through colkeyL (LDS uint atomicMax) -> 256 global atomics
// per block (NEVER funnel same-address atomics: R18 +20us).
// Grid 1440 = 36 rounds x 40 (k,type); bid%40 -> same XCD per (k,type).
// Neg uses rounds 0..31 (8 i_blk x 4 jq), pos rounds 0..35 (triangle pairs).
template<int NT, bool POS>
__device__ __forceinline__ void select_core(
        const char* __restrict__ S8B,
        const float* __restrict__ xx,
        const int* __restrict__ idxA,
        const int* __restrict__ idxB,
        unsigned int* __restrict__ outKey,
        const int i0, const int j0, const bool doCol,
        uint4 (*Bt4)[512], float* yyL, float* xxL, unsigned int* colkeyL,
        const int tid, const int w, const int lane15, const int quad) {
    // ---- staging geometry: 2 copies per wave per tile, 4 rows per copy ----
    const int rl  = (tid & 63) >> 4;
    const int cch = tid & 15;
    int rloc[2], soff[2];
#pragma unroll
    for (int c = 0; c < 2; ++c) {
        rloc[c] = (w * 2 + c) * 4 + rl;
        soff[c] = (cch ^ (rloc[c] & 15)) << 4;
    }

    // ---- preload ALL staging row indices (rows < 65536 -> 2x16-bit pack) ---
    uint32_t g_pk[NT];
#pragma unroll
    for (int t = 0; t < NT; ++t) {
        const uint32_t a0 = (uint32_t)idxB[j0 + t * 32 + rloc[0]];
        const uint32_t a1 = (uint32_t)idxB[j0 + t * 32 + rloc[1]];
        g_pk[t] = (a0 & 0xFFFFu) | (a1 << 16);
    }

    // ---- yy (and for POS: xx + colkey init) tables ----
#pragma unroll
    for (int t = 0; t < NT / 8; ++t) {
        const int jj = t * 256 + tid;
        yyL[jj] = xx[idxB[j0 + jj]];
    }
    if (POS) {
        xxL[tid] = xx[idxA[i0 + tid]];
        colkeyL[tid] = 0u;
    }

    // ---- A fragments, sign-flipped (A-scale 2^1 -> MFMA gives -2*x.y) ----
    Frag8 A_reg[4][2];
#pragma unroll
    for (int si = 0; si < 4; ++si) {
        const int gi = idxA[i0 + w * 64 + si * 16 + lane15];
        const char* rb = S8B + ((size_t)(uint32_t)gi << 8) + quad * 32;
#pragma unroll
        for (int s = 0; s < 2; ++s) {
            A_reg[si][s].q[0] = *(const uint4*)(rb + s * 128);
            A_reg[si][s].q[1] = *(const uint4*)(rb + s * 128 + 16);
            negA(A_reg[si][s]);
        }
    }

    const int bidx0 = lane15 * 16 + ((quad * 2) ^ lane15);

    float bestv[16];
    const float binit = POS ? -3.4e38f : 3.4e38f;
#pragma unroll
    for (int t = 0; t < 16; ++t) bestv[t] = binit;

    // ---- prologue: issue tiles 0 and 1 ----
#pragma unroll
    for (int t = 0; t < 2; ++t) {
        char* lb = (char*)Bt4[t] + (w * 2) * 1024;
        async_copy16(S8B + ((size_t)(g_pk[t] & 0xFFFFu) << 8) + soff[0], lb);
        async_copy16(S8B + ((size_t)(g_pk[t] >> 16) << 8) + soff[1], lb + 1024);
    }
    __syncthreads();   // one-time full drain: tiles 0,1 in LDS; tables visible

#pragma unroll
    for (int jc = 0; jc < NT; ++jc) {
        if (jc) {
            if (jc == NT - 1) VMCNT0(); else VMCNT2();
            __builtin_amdgcn_s_barrier();
            __builtin_amdgcn_sched_barrier(0);
        }
        const float yv0 = yyL[(jc << 5) + lane15];
        const float yv1 = yyL[(jc << 5) + 16 + lane15];

        if (jc < NT - 2) {
            const uint32_t pk = g_pk[jc + 2];
            char* lb = (char*)Bt4[(jc + 2) % 3] + (w * 2) * 1024;
            async_copy16(S8B + ((size_t)(pk & 0xFFFFu) << 8) + soff[0], lb);
            async_copy16(S8B + ((size_t)(pk >> 16) << 8) + soff[1], lb + 1024);
        }

        // ---- compute: 2 K-steps of 128; first K-step carries yy in C ----
        const floatx4 yv4_0 = {yv0, yv0, yv0, yv0};
        const floatx4 yv4_1 = {yv1, yv1, yv1, yv1};
        floatx4 acc[2][4];
        {
            Frag8 bf0, bf1;
            bf0.q[0] = Bt4[jc % 3][bidx0];
            bf0.q[1] = Bt4[jc % 3][bidx0 ^ 1];
            bf1.q[0] = Bt4[jc % 3][bidx0 + 256];
            bf1.q[1] = Bt4[jc % 3][(bidx0 ^ 1) + 256];
#pragma unroll
            for (int si = 0; si < 4; ++si)
                acc[0][si] = __builtin_amdgcn_mfma_scale_f32_16x16x128_f8f6f4(
                    A_reg[si][0].v, bf0.v, yv4_0, 0, 0, 0, SCALE2, 0, SCALE1);
#pragma unroll
            for (int si = 0; si < 4; ++si)
                acc[1][si] = __builtin_amdgcn_mfma_scale_f32_16x16x128_f8f6f4(
                    A_reg[si][0].v, bf1.v, yv4_1, 0, 0, 0, SCALE2, 0, SCALE1);
        }
        {
            Frag8 bf0, bf1;
            bf0.q[0] = Bt4[jc % 3][bidx0 ^ 8];
            bf0.q[1] = Bt4[jc % 3][bidx0 ^ 9];
            bf1.q[0] = Bt4[jc % 3][(bidx0 ^ 8) + 256];
            bf1.q[1] = Bt4[jc % 3][(bidx0 ^ 9) + 256];
#pragma unroll
            for (int si = 0; si < 4; ++si)
                acc[0][si] = __builtin_amdgcn_mfma_scale_f32_16x16x128_f8f6f4(
                    A_reg[si][1].v, bf0.v, acc[0][si], 0, 0, 0, SCALE2, 0, SCALE1);
#pragma unroll
            for (int si = 0; si < 4; ++si)
                acc[1][si] = __builtin_amdgcn_mfma_scale_f32_16x16x128_f8f6f4(
                    A_reg[si][1].v, bf1.v, acc[1][si], 0, 0, 0, SCALE2, 0, SCALE1);
        }

        // ---- epilogue ----
        const uint32_t jb0 = (uint32_t)((j0 + (jc << 5)) | lane15);
        const uint32_t jb1 = jb0 | 16u;
        if (POS) {
            // encode FULL d^2 = acc + xx_row; row-merge (idx=j) + col-merge
            // (idx=row) on the same truncated value -> mixable in hp.
            float cm0 = -3.4e38f, cm1 = -3.4e38f;
#pragma unroll
            for (int si = 0; si < 4; ++si)
#pragma unroll
                for (int r = 0; r < 4; ++r) {
                    const int rowl = w * 64 + si * 16 + quad * 4 + r;
                    const float xv = xxL[rowl & 255];
                    const uint32_t ib = (uint32_t)(i0 + rowl);
                    const uint32_t e0 =
                        __float_as_uint(acc[0][si][r] + xv) & 0xFFFFF800u;
                    const uint32_t e1 =
                        __float_as_uint(acc[1][si][r] + xv) & 0xFFFFF800u;
                    const int slot = si * 4 + r;
                    bestv[slot] = fmaxf(fmaxf(bestv[slot],
                        __uint_as_float(e0 | jb0)), __uint_as_float(e1 | jb1));
                    cm0 = fmaxf(cm0, __uint_as_float(e0 | ib));
                    cm1 = fmaxf(cm1, __uint_as_float(e1 | ib));
                }
            if (doCol) {
                // reduce over quads (cols live in lane15; quads hold rows)
                cm0 = fmaxf(cm0, __shfl_xor(cm0, 16));
                cm0 = fmaxf(cm0, __shfl_xor(cm0, 32));
                cm1 = fmaxf(cm1, __shfl_xor(cm1, 16));
                cm1 = fmaxf(cm1, __shfl_xor(cm1, 32));
                if (quad == 0) {
                    atomicMax(&colkeyL[(jc << 5) + lane15], mkey(cm0));
                    atomicMax(&colkeyL[(jc << 5) + 16 + lane15], mkey(cm1));
                }
            }
        } else {
#pragma unroll
            for (int si = 0; si < 4; ++si)
#pragma unroll
                for (int r = 0; r < 4; ++r) {
                    const float e0 = __uint_as_float(
                        (__float_as_uint(acc[0][si][r]) & 0xFFFFF800u) | jb0);
                    const float e1 = __uint_as_float(
                        (__float_as_uint(acc[1][si][r]) & 0xFFFFF800u) | jb1);
                    const int slot = si * 4 + r;
                    bestv[slot] = fminf(fminf(bestv[slot], e0), e1);
                }
        }
    }

    // ---- row-path reduce over the 16 column-lanes + global merge ----
#pragma unroll
    for (int slot = 0; slot < 16; ++slot) {
#pragma unroll
        for (int off = 1; off < 16; off <<= 1) {
            const float ov = __shfl_xor(bestv[slot], off);
            bestv[slot] = POS ? fmaxf(bestv[slot], ov) : fminf(bestv[slot], ov);
        }
    }
    if (lane15 == 0) {
#pragma unroll
        for (int si = 0; si < 4; ++si)
#pragma unroll
            for (int r = 0; r < 4; ++r) {
                const int row = w * 64 + si * 16 + quad * 4 + r;
                const uint32_t key = mkey(bestv[si * 4 + r]);
                if (POS) atomicMax(&outKey[i0 + row], key);
                else     atomicMin(&outKey[i0 + row], key);
            }
    }
    // ---- col-path global merge (off-diagonal pos blocks only) ----
    if (POS && doCol) {
        __syncthreads();   // all waves' colkeyL atomics done
        const unsigned int u = colkeyL[tid];
        if (u) atomicMax(&outKey[j0 + tid], u);
    }
}

__global__ __launch_bounds__(256, 3) void select_k(
        const unsigned int* __restrict__ S8,
        const float* __restrict__ xx,
        const int* __restrict__ pos_idx,
        const int* __restrict__ neg_idx,
        unsigned int* __restrict__ hp,
        unsigned int* __restrict__ hn) {
    __shared__ __align__(16) uint4 Bt4[3][512];   // 24 KiB ring
    __shared__ float yyL[512];                    // 2 KiB
    __shared__ float xxL[256];                    // 1 KiB (pos only)
    __shared__ unsigned int colkeyL[256];         // 1 KiB (pos only)

    const int tid    = threadIdx.x;
    const int w      = tid >> 6;
    const int lane15 = tid & 15;
    const int quad   = (tid & 63) >> 4;

    const int bid  = blockIdx.x;      // 1440 = 36 rounds x 40 (k,type)
    const int ctid = bid % 40;
    const int r    = bid / 40;        // 0..35
    const int k    = ctid >> 1;
    const int isNeg = ctid & 1;
    const char* S8B = (const char*)S8;

    if (isNeg) {
        if (r >= 32) return;                       // 4 dead rounds per class
        const int i0 = (r >> 2) * 256;
        const int j0 = (r & 3) * 512;
        select_core<16, false>(S8B, xx, pos_idx + k * P_POS,
                               neg_idx + k * P_POS, hn + k * P_POS,
                               i0, j0, false, Bt4, yyL, xxL, colkeyL,
                               tid, w, lane15, quad);
    } else {
        int t = r, a = 0;                          // triangle pair (a<=b)
        while (t >= 8 - a) { t -= 8 - a; ++a; }
        const int b = a + t;
        select_core<8, true>(S8B, xx, pos_idx + k * P_POS,
                             pos_idx + k * P_POS, hp + k * P_POS,
                             a * 256, b * 256, a < b, Bt4, yyL, xxL, colkeyL,
                             tid, w, lane15, quad);
    }
}

// ------- Kernel 3: per-anchor pdist from fp8 table (16 lanes/anchor) --------
// R24: per-block partial sum (640 floats) instead of terms[40960] round-trip.
#define ACC16(UA, UP, UN)                                                     \
    {                                                                         \
        float xa, d;                                                          \
        xa = __builtin_amdgcn_cvt_f32_fp8((int)(UA), 0);                      \
        d = xa - __builtin_amdgcn_cvt_f32_fp8((int)(UP), 0); dp += d * d;     \
        d = xa - __builtin_amdgcn_cvt_f32_fp8((int)(UN), 0); dn += d * d;     \
        xa = __builtin_amdgcn_cvt_f32_fp8((int)(UA), 1);                      \
        d = xa - __builtin_amdgcn_cvt_f32_fp8((int)(UP), 1); dp += d * d;     \
        d = xa - __builtin_amdgcn_cvt_f32_fp8((int)(UN), 1); dn += d * d;     \
        xa = __builtin_amdgcn_cvt_f32_fp8((int)(UA), 2);                      \
        d = xa - __builtin_amdgcn_cvt_f32_fp8((int)(UP), 2); dp += d * d;     \
        d = xa - __builtin_amdgcn_cvt_f32_fp8((int)(UN), 2); dn += d * d;     \
        xa = __builtin_amdgcn_cvt_f32_fp8((int)(UA), 3);                      \
        d = xa - __builtin_amdgcn_cvt_f32_fp8((int)(UP), 3); dp += d * d;     \
        d = xa - __builtin_amdgcn_cvt_f32_fp8((int)(UN), 3); dn += d * d;     \
    }

__global__ __launch_bounds__(256) void loss_k(
        const unsigned int* __restrict__ S8,
        const int* __restrict__ pos_idx,
        const int* __restrict__ neg_idx,
        const unsigned int* __restrict__ hp,
        const unsigned int* __restrict__ hn,
        float* __restrict__ partials) {
    __shared__ float sm[16];
    const int tid    = threadIdx.x;
    const int lane15 = tid & 15;
    const int grp    = tid >> 4;               // 0..15
    const char* S8B  = (const char*)S8;
    float lsum = 0.f;
#pragma unroll
    for (int c = 0; c < 4; ++c) {
        const int a = ((int)blockIdx.x * 4 + c) * 16 + grp;   // 0..40959
        const int k = a >> 11;
        const int i = a & 2047;
        const int* pidx = pos_idx + (k << 11);
        const int* nidx = neg_idx + (k << 11);
        const unsigned int kp = hp[a], kn = hn[a];
        const int jp = (int)((kp & 0x80000000u) ? (kp & 2047u) : ((~kp) & 2047u));
        const int jn = (int)((kn & 0x80000000u) ? (kn & 2047u) : ((~kn) & 2047u));
        const int ga = pidx[i];
        const int gp = pidx[jp];
        const int gn = nidx[jn];

        const uint4 va = *(const uint4*)(S8B + ((size_t)(uint32_t)ga << 8) + lane15 * 16);
        const uint4 vp = *(const uint4*)(S8B + ((size_t)(uint32_t)gp << 8) + lane15 * 16);
        const uint4 vn = *(const uint4*)(S8B + ((size_t)(uint32_t)gn << 8) + lane15 * 16);

        float dp = 0.f, dn = 0.f;
        ACC16(va.x, vp.x, vn.x)
        ACC16(va.y, vp.y, vn.y)
        ACC16(va.z, vp.z, vn.z)
        ACC16(va.w, vp.w, vn.w)

#pragma unroll
        for (int off = 1; off < 16; off <<= 1) {
            dp += __shfl_xor(dp, off);
            dn += __shfl_xor(dn, off);
        }
        if (lane15 == 0) {
            const float d_p = sqrtf(fmaxf(dp, 0.f) + EPS_D);
            const float d_n = sqrtf(fmaxf(dn, 0.f) + EPS_D);
            lsum += fmaxf(MARGIN_F + d_p - d_n, 0.f);
        }
    }
    if (lane15 == 0) sm[grp] = lsum;
    __syncthreads();
    if (tid == 0) {
        float s = 0.f;
#pragma unroll
        for (int g = 0; g < 16; ++g) s += sm[g];
        partials[blockIdx.x] = s;
    }
}

// ---------------- Kernel 4: tiny final reduction (640 partials) -------------
__global__ __launch_bounds__(64) void reduce_k(
        const float* __restrict__ partials, float* __restrict__ out) {
    const int tid = threadIdx.x;
    float s = 0.f;
    for (int i = tid; i < 640; i += 64) s += partials[i];
#pragma unroll
    for (int off = 32; off; off >>= 1) s += __shfl_down(s, off);
    if (tid == 0) out[0] = s * (1.0f / (float)P_POS);
}

extern "C" void kernel_launch(void* const* d_in, const int* in_sizes, int n_in,
                              void* d_out, int out_size, void* d_ws, size_t ws_size,
                              hipStream_t stream) {
    const float* feat    = (const float*)d_in[0];
    const int*   pos_idx = (const int*)d_in[1];
    const int*   neg_idx = (const int*)d_in[2];

    char* ws = (char*)d_ws;
    unsigned int* S8 = (unsigned int*)ws;                     // 16 MiB fp8 table
    float*        xx = (float*)(ws + 16777216);               // 256 KiB norms
    unsigned int* hp = (unsigned int*)(ws + 17039360);        // 160 KiB keys
    unsigned int* hn = (unsigned int*)(ws + 17203200);        // 160 KiB keys
    float*  partials = (float*)(ws + 17367040);               // 2.5 KiB

    sigmoid_norm_k<<<2048, 256, 0, stream>>>(feat, S8, xx, hp, hn);

    select_k<<<36 * 40, 256, 0, stream>>>(S8, xx, pos_idx, neg_idx, hp, hn);

    loss_k<<<640, 256, 0, stream>>>(S8, pos_idx, neg_idx, hp, hn, partials);

    reduce_k<<<1, 64, 0, stream>>>(partials, (float*)d_out);
}

// Round 10
// 209.395 us; speedup vs baseline: 1.1743x; 1.1743x over previous
//
#include <hip/hip_runtime.h>
#include <stdint.h>

#define M_ROWS 65536
#define C_DIM  256
#define K_CLS  20
#define P_POS  2048
#define MARGIN_F 0.3f
#define EPS_D (0.0001f / 256.0f)
#define SCALE1 0x7F7F7F7Fu   /* e8m0 127 = 2^0 in all four bytes */
#define SCALE2 0x80808080u   /* e8m0 128 = 2^1 in all four bytes (A operand) */

typedef float floatx4 __attribute__((ext_vector_type(4)));
typedef int   intx8   __attribute__((ext_vector_type(8)));
union Frag8 { intx8 v; uint4 q[2]; };

// async 16B/lane global -> LDS (wave-uniform LDS base + lane*16)
__device__ __forceinline__ void async_copy16(const void* g, void* l) {
    __builtin_amdgcn_global_load_lds(
        (const __attribute__((address_space(1))) void*)g,
        (__attribute__((address_space(3))) void*)l, 16, 0, 0);
}
__device__ __forceinline__ float sigm(float x) { return 1.f / (1.f + __expf(-x)); }

__device__ __forceinline__ void negA(Frag8& f) {
#pragma unroll
    for (int t = 0; t < 8; ++t) f.v[t] ^= (int)0x80808080u;
}
__device__ __forceinline__ unsigned int mkey(float f) {
    const uint32_t u = __float_as_uint(f);
    return (u & 0x80000000u) ? ~u : (u | 0x80000000u);
}

#define VMCNT2() asm volatile("s_waitcnt vmcnt(2)" ::: "memory")
#define VMCNT0() asm volatile("s_waitcnt vmcnt(0)" ::: "memory")

// ------- Kernel 1: sigmoid -> fp8 e4m3 table + fp8-exact row norms ----------
__global__ __launch_bounds__(256) void sigmoid_norm_k(
        const float* __restrict__ feat,
        unsigned int* __restrict__ S8,     // [M][64] uint = 256 fp8/row
        float* __restrict__ xx,
        unsigned int* __restrict__ hp,
        unsigned int* __restrict__ hn) {
    {
        const int idx = blockIdx.x * 256 + threadIdx.x;
        if (idx < K_CLS * P_POS) { hp[idx] = 0u; hn[idx] = 0xFFFFFFFFu; }
    }
    const int wave = threadIdx.x >> 6, lane = threadIdx.x & 63;
    for (int g = blockIdx.x; g < M_ROWS / 4; g += 2048) {
        const int row = g * 4 + wave;
        const float4 v = *(const float4*)(feat + (size_t)row * C_DIM + lane * 4);

        const int p01 = __builtin_amdgcn_cvt_pk_fp8_f32(sigm(v.x), sigm(v.y), 0, false);
        const int p23 = __builtin_amdgcn_cvt_pk_fp8_f32(sigm(v.z), sigm(v.w), 0, false);
        S8[(size_t)row * 64 + lane] =
            (unsigned int)(p01 & 0xFFFF) | ((unsigned int)p23 << 16);

        const float q0 = __builtin_amdgcn_cvt_f32_fp8(p01, 0);
        const float q1 = __builtin_amdgcn_cvt_f32_fp8(p01, 1);
        const float q2 = __builtin_amdgcn_cvt_f32_fp8(p23, 0);
        const float q3 = __builtin_amdgcn_cvt_f32_fp8(p23, 1);
        float sum = q0 * q0 + q1 * q1 + q2 * q2 + q3 * q3;
#pragma unroll
        for (int off = 32; off; off >>= 1) sum += __shfl_down(sum, off);
        if (lane == 0) xx[row] = sum;
    }
}

// ----- Kernel 2a: NEG distance-GEMM + argmin (R21 core VERBATIM, 20 cls) ----
// R25: R24's symmetry math was CORRECT (absmax 0) but inlining POS+NEG cores
// into one kernel spilled (WRITE 17.8->169.7 MB, the R19 signature; allocator
// sizes for the union of both paths). Fix: two standalone kernels.
// Grid 640 = 32 (i_blk,jq) x 20 k. 10240 tiles.
__global__ __launch_bounds__(256, 3) void neg_select_k(
        const unsigned int* __restrict__ S8,
        const float* __restrict__ xx,
        const int* __restrict__ pos_idx,
        const int* __restrict__ neg_idx,
        unsigned int* __restrict__ hn) {
    __shared__ __align__(16) uint4 Bt4[3][512];   // 24 KiB ring
    __shared__ float yyL[512];                    // 2 KiB

    const int tid    = threadIdx.x;
    const int w      = tid >> 6;
    const int lane   = tid & 63;
    const int lane15 = lane & 15;
    const int quad   = lane >> 4;

    const int bid   = blockIdx.x;      // 640 = 32 (i_blk,jq) x 20 k
    const int k     = bid % 20;
    const int rest  = bid / 20;        // 0..31
    const int i_blk = rest >> 2;
    const int jq    = rest & 3;
    const int i0    = i_blk * 256;
    const int j0    = jq * 512;        // 16 tiles of 32 j

    const int* __restrict__ idxA = pos_idx + k * P_POS;
    const int* __restrict__ idxB = neg_idx + k * P_POS;
    unsigned int* outKey         = hn + k * P_POS;

    const char* S8B = (const char*)S8;

    const int rl  = lane >> 4;
    const int cch = lane & 15;
    int rloc[2], soff[2];
#pragma unroll
    for (int c = 0; c < 2; ++c) {
        rloc[c] = (w * 2 + c) * 4 + rl;
        soff[c] = (cch ^ (rloc[c] & 15)) << 4;
    }

    uint32_t g_pk[16];
#pragma unroll
    for (int t = 0; t < 16; ++t) {
        const uint32_t a0 = (uint32_t)idxB[j0 + t * 32 + rloc[0]];
        const uint32_t a1 = (uint32_t)idxB[j0 + t * 32 + rloc[1]];
        g_pk[t] = (a0 & 0xFFFFu) | (a1 << 16);
    }
#pragma unroll
    for (int t = 0; t < 2; ++t) {
        const int jj = t * 256 + tid;
        yyL[jj] = xx[idxB[j0 + jj]];
    }

    Frag8 A_reg[4][2];
#pragma unroll
    for (int si = 0; si < 4; ++si) {
        const int gi = idxA[i0 + w * 64 + si * 16 + lane15];
        const char* rb = S8B + ((size_t)(uint32_t)gi << 8) + quad * 32;
#pragma unroll
        for (int s = 0; s < 2; ++s) {
            A_reg[si][s].q[0] = *(const uint4*)(rb + s * 128);
            A_reg[si][s].q[1] = *(const uint4*)(rb + s * 128 + 16);
            negA(A_reg[si][s]);
        }
    }

    const int bidx0 = lane15 * 16 + ((quad * 2) ^ lane15);

    float bestv[16];
#pragma unroll
    for (int t = 0; t < 16; ++t) bestv[t] = 3.4e38f;

#pragma unroll
    for (int t = 0; t < 2; ++t) {
        char* lb = (char*)Bt4[t] + (w * 2) * 1024;
        async_copy16(S8B + ((size_t)(g_pk[t] & 0xFFFFu) << 8) + soff[0], lb);
        async_copy16(S8B + ((size_t)(g_pk[t] >> 16) << 8) + soff[1], lb + 1024);
    }
    __syncthreads();

#pragma unroll
    for (int jc = 0; jc < 16; ++jc) {
        if (jc) {
            if (jc == 15) VMCNT0(); else VMCNT2();
            __builtin_amdgcn_s_barrier();
            __builtin_amdgcn_sched_barrier(0);
        }
        const float yv0 = yyL[(jc << 5) + lane15];
        const float yv1 = yyL[(jc << 5) + 16 + lane15];

        if (jc < 14) {
            const uint32_t pk = g_pk[jc + 2];
            char* lb = (char*)Bt4[(jc + 2) % 3] + (w * 2) * 1024;
            async_copy16(S8B + ((size_t)(pk & 0xFFFFu) << 8) + soff[0], lb);
            async_copy16(S8B + ((size_t)(pk >> 16) << 8) + soff[1], lb + 1024);
        }

        const floatx4 yv4_0 = {yv0, yv0, yv0, yv0};
        const floatx4 yv4_1 = {yv1, yv1, yv1, yv1};
        floatx4 acc[2][4];
        {
            Frag8 bf0, bf1;
            bf0.q[0] = Bt4[jc % 3][bidx0];
            bf0.q[1] = Bt4[jc % 3][bidx0 ^ 1];
            bf1.q[0] = Bt4[jc % 3][bidx0 + 256];
            bf1.q[1] = Bt4[jc % 3][(bidx0 ^ 1) + 256];
#pragma unroll
            for (int si = 0; si < 4; ++si)
                acc[0][si] = __builtin_amdgcn_mfma_scale_f32_16x16x128_f8f6f4(
                    A_reg[si][0].v, bf0.v, yv4_0, 0, 0, 0, SCALE2, 0, SCALE1);
#pragma unroll
            for (int si = 0; si < 4; ++si)
                acc[1][si] = __builtin_amdgcn_mfma_scale_f32_16x16x128_f8f6f4(
                    A_reg[si][0].v, bf1.v, yv4_1, 0, 0, 0, SCALE2, 0, SCALE1);
        }
        {
            Frag8 bf0, bf1;
            bf0.q[0] = Bt4[jc % 3][bidx0 ^ 8];
            bf0.q[1] = Bt4[jc % 3][bidx0 ^ 9];
            bf1.q[0] = Bt4[jc % 3][(bidx0 ^ 8) + 256];
            bf1.q[1] = Bt4[jc % 3][(bidx0 ^ 9) + 256];
#pragma unroll
            for (int si = 0; si < 4; ++si)
                acc[0][si] = __builtin_amdgcn_mfma_scale_f32_16x16x128_f8f6f4(
                    A_reg[si][1].v, bf0.v, acc[0][si], 0, 0, 0, SCALE2, 0, SCALE1);
#pragma unroll
            for (int si = 0; si < 4; ++si)
                acc[1][si] = __builtin_amdgcn_mfma_scale_f32_16x16x128_f8f6f4(
                    A_reg[si][1].v, bf1.v, acc[1][si], 0, 0, 0, SCALE2, 0, SCALE1);
        }

        const uint32_t jb0 = (uint32_t)((j0 + (jc << 5)) | lane15);
        const uint32_t jb1 = jb0 | 16u;
#pragma unroll
        for (int si = 0; si < 4; ++si)
#pragma unroll
            for (int r = 0; r < 4; ++r) {
                const float e0 = __uint_as_float(
                    (__float_as_uint(acc[0][si][r]) & 0xFFFFF800u) | jb0);
                const float e1 = __uint_as_float(
                    (__float_as_uint(acc[1][si][r]) & 0xFFFFF800u) | jb1);
                const int slot = si * 4 + r;
                bestv[slot] = fminf(fminf(bestv[slot], e0), e1);
            }
    }

#pragma unroll
    for (int slot = 0; slot < 16; ++slot) {
#pragma unroll
        for (int off = 1; off < 16; off <<= 1) {
            const float ov = __shfl_xor(bestv[slot], off);
            bestv[slot] = fminf(bestv[slot], ov);
        }
    }
    if (lane15 == 0) {
#pragma unroll
        for (int si = 0; si < 4; ++si)
#pragma unroll
            for (int r = 0; r < 4; ++r) {
                const int row = w * 64 + si * 16 + quad * 4 + r;
                atomicMin(&outKey[i0 + row], mkey(bestv[si * 4 + r]));
            }
    }
}

// ----- Kernel 2b: POS triangle distance-GEMM + argmax (symmetry halved) -----
// Upper triangle of 256x256 super-tiles: 36 (a<=b) pairs x 20 k = 720 blocks,
// 8 tiles each (5760 tiles; full grid was 10240). Off-diagonal merges BOTH
// row-wise (hp[i0+row], idx=j) and col-wise (hp[j0+col], idx=row) -- mixable
// because we encode FULL d^2 = acc + xx_row (xxL broadcast + fadd), truncated
// identically for both paths (validated absmax=0 in R24).
// Col merge funnels through colkeyL (LDS atomicMax) -> 256 global atomics.
__global__ __launch_bounds__(256, 3) void pos_select_k(
        const unsigned int* __restrict__ S8,
        const float* __restrict__ xx,
        const int* __restrict__ pos_idx,
        unsigned int* __restrict__ hp) {
    __shared__ __align__(16) uint4 Bt4[3][512];   // 24 KiB ring
    __shared__ float yyL[256];                    // 1 KiB
    __shared__ float xxL[256];                    // 1 KiB
    __shared__ unsigned int colkeyL[256];         // 1 KiB

    const int tid    = threadIdx.x;
    const int w      = tid >> 6;
    const int lane   = tid & 63;
    const int lane15 = lane & 15;
    const int quad   = lane >> 4;

    const int bid = blockIdx.x;       // 720 = 36 pairs x 20 k
    const int k   = bid % 20;
    int t36 = bid / 20, a = 0;        // triangle pair (a<=b)
    while (t36 >= 8 - a) { t36 -= 8 - a; ++a; }
    const int b = a + t36;
    const bool doCol = (a < b);
    const int i0 = a * 256;
    const int j0 = b * 256;           // 8 tiles of 32 j

    const int* __restrict__ idx = pos_idx + k * P_POS;
    unsigned int* outKey        = hp + k * P_POS;

    const char* S8B = (const char*)S8;

    const int rl  = lane >> 4;
    const int cch = lane & 15;
    int rloc[2], soff[2];
#pragma unroll
    for (int c = 0; c < 2; ++c) {
        rloc[c] = (w * 2 + c) * 4 + rl;
        soff[c] = (cch ^ (rloc[c] & 15)) << 4;
    }

    uint32_t g_pk[8];
#pragma unroll
    for (int t = 0; t < 8; ++t) {
        const uint32_t a0 = (uint32_t)idx[j0 + t * 32 + rloc[0]];
        const uint32_t a1 = (uint32_t)idx[j0 + t * 32 + rloc[1]];
        g_pk[t] = (a0 & 0xFFFFu) | (a1 << 16);
    }
    yyL[tid] = xx[idx[j0 + tid]];
    xxL[tid] = xx[idx[i0 + tid]];
    colkeyL[tid] = 0u;

    Frag8 A_reg[4][2];
#pragma unroll
    for (int si = 0; si < 4; ++si) {
        const int gi = idx[i0 + w * 64 + si * 16 + lane15];
        const char* rb = S8B + ((size_t)(uint32_t)gi << 8) + quad * 32;
#pragma unroll
        for (int s = 0; s < 2; ++s) {
            A_reg[si][s].q[0] = *(const uint4*)(rb + s * 128);
            A_reg[si][s].q[1] = *(const uint4*)(rb + s * 128 + 16);
            negA(A_reg[si][s]);
        }
    }

    const int bidx0 = lane15 * 16 + ((quad * 2) ^ lane15);

    float bestv[16];
#pragma unroll
    for (int t = 0; t < 16; ++t) bestv[t] = -3.4e38f;

#pragma unroll
    for (int t = 0; t < 2; ++t) {
        char* lb = (char*)Bt4[t] + (w * 2) * 1024;
        async_copy16(S8B + ((size_t)(g_pk[t] & 0xFFFFu) << 8) + soff[0], lb);
        async_copy16(S8B + ((size_t)(g_pk[t] >> 16) << 8) + soff[1], lb + 1024);
    }
    __syncthreads();   // tiles 0,1 landed; yyL/xxL/colkeyL visible

#pragma unroll
    for (int jc = 0; jc < 8; ++jc) {
        if (jc) {
            if (jc == 7) VMCNT0(); else VMCNT2();
            __builtin_amdgcn_s_barrier();
            __builtin_amdgcn_sched_barrier(0);
        }
        const float yv0 = yyL[(jc << 5) + lane15];
        const float yv1 = yyL[(jc << 5) + 16 + lane15];

        if (jc < 6) {
            const uint32_t pk = g_pk[jc + 2];
            char* lb = (char*)Bt4[(jc + 2) % 3] + (w * 2) * 1024;
            async_copy16(S8B + ((size_t)(pk & 0xFFFFu) << 8) + soff[0], lb);
            async_copy16(S8B + ((size_t)(pk >> 16) << 8) + soff[1], lb + 1024);
        }

        const floatx4 yv4_0 = {yv0, yv0, yv0, yv0};
        const floatx4 yv4_1 = {yv1, yv1, yv1, yv1};
        floatx4 acc[2][4];
        {
            Frag8 bf0, bf1;
            bf0.q[0] = Bt4[jc % 3][bidx0];
            bf0.q[1] = Bt4[jc % 3][bidx0 ^ 1];
            bf1.q[0] = Bt4[jc % 3][bidx0 + 256];
            bf1.q[1] = Bt4[jc % 3][(bidx0 ^ 1) + 256];
#pragma unroll
            for (int si = 0; si < 4; ++si)
                acc[0][si] = __builtin_amdgcn_mfma_scale_f32_16x16x128_f8f6f4(
                    A_reg[si][0].v, bf0.v, yv4_0, 0, 0, 0, SCALE2, 0, SCALE1);
#pragma unroll
            for (int si = 0; si < 4; ++si)
                acc[1][si] = __builtin_amdgcn_mfma_scale_f32_16x16x128_f8f6f4(
                    A_reg[si][0].v, bf1.v, yv4_1, 0, 0, 0, SCALE2, 0, SCALE1);
        }
        {
            Frag8 bf0, bf1;
            bf0.q[0] = Bt4[jc % 3][bidx0 ^ 8];
            bf0.q[1] = Bt4[jc % 3][bidx0 ^ 9];
            bf1.q[0] = Bt4[jc % 3][(bidx0 ^ 8) + 256];
            bf1.q[1] = Bt4[jc % 3][(bidx0 ^ 9) + 256];
#pragma unroll
            for (int si = 0; si < 4; ++si)
                acc[0][si] = __builtin_amdgcn_mfma_scale_f32_16x16x128_f8f6f4(
                    A_reg[si][1].v, bf0.v, acc[0][si], 0, 0, 0, SCALE2, 0, SCALE1);
#pragma unroll
            for (int si = 0; si < 4; ++si)
                acc[1][si] = __builtin_amdgcn_mfma_scale_f32_16x16x128_f8f6f4(
                    A_reg[si][1].v, bf1.v, acc[1][si], 0, 0, 0, SCALE2, 0, SCALE1);
        }

        // epilogue: FULL d^2 = acc + xx_row, truncate, row- and col-merge
        const uint32_t jb0 = (uint32_t)((j0 + (jc << 5)) | lane15);
        const uint32_t jb1 = jb0 | 16u;
        float cm0 = -3.4e38f, cm1 = -3.4e38f;
#pragma unroll
        for (int si = 0; si < 4; ++si)
#pragma unroll
            for (int r = 0; r < 4; ++r) {
                const int rowl = w * 64 + si * 16 + quad * 4 + r;
                const float xv = xxL[rowl];
                const uint32_t ib = (uint32_t)(i0 + rowl);
                const uint32_t e0 =
                    __float_as_uint(acc[0][si][r] + xv) & 0xFFFFF800u;
                const uint32_t e1 =
                    __float_as_uint(acc[1][si][r] + xv) & 0xFFFFF800u;
                const int slot = si * 4 + r;
                bestv[slot] = fmaxf(fmaxf(bestv[slot],
                    __uint_as_float(e0 | jb0)), __uint_as_float(e1 | jb1));
                cm0 = fmaxf(cm0, __uint_as_float(e0 | ib));
                cm1 = fmaxf(cm1, __uint_as_float(e1 | ib));
            }
        if (doCol) {
            cm0 = fmaxf(cm0, __shfl_xor(cm0, 16));
            cm0 = fmaxf(cm0, __shfl_xor(cm0, 32));
            cm1 = fmaxf(cm1, __shfl_xor(cm1, 16));
            cm1 = fmaxf(cm1, __shfl_xor(cm1, 32));
            if (quad == 0) {
                atomicMax(&colkeyL[(jc << 5) + lane15], mkey(cm0));
                atomicMax(&colkeyL[(jc << 5) + 16 + lane15], mkey(cm1));
            }
        }
    }

    // row-path reduce + global merge
#pragma unroll
    for (int slot = 0; slot < 16; ++slot) {
#pragma unroll
        for (int off = 1; off < 16; off <<= 1) {
            const float ov = __shfl_xor(bestv[slot], off);
            bestv[slot] = fmaxf(bestv[slot], ov);
        }
    }
    if (lane15 == 0) {
#pragma unroll
        for (int si = 0; si < 4; ++si)
#pragma unroll
            for (int r = 0; r < 4; ++r) {
                const int row = w * 64 + si * 16 + quad * 4 + r;
                atomicMax(&outKey[i0 + row], mkey(bestv[si * 4 + r]));
            }
    }
    // col-path global merge (off-diagonal only)
    if (doCol) {
        __syncthreads();
        const unsigned int u = colkeyL[tid];
        if (u) atomicMax(&outKey[j0 + tid], u);
    }
}

// ------- Kernel 3: per-anchor pdist from fp8 table (16 lanes/anchor) --------
#define ACC16(UA, UP, UN)                                                     \
    {                                                                         \
        float xa, d;                                                          \
        xa = __builtin_amdgcn_cvt_f32_fp8((int)(UA), 0);                      \
        d = xa - __builtin_amdgcn_cvt_f32_fp8((int)(UP), 0); dp += d * d;     \
        d = xa - __builtin_amdgcn_cvt_f32_fp8((int)(UN), 0); dn += d * d;     \
        xa = __builtin_amdgcn_cvt_f32_fp8((int)(UA), 1);                      \
        d = xa - __builtin_amdgcn_cvt_f32_fp8((int)(UP), 1); dp += d * d;     \
        d = xa - __builtin_amdgcn_cvt_f32_fp8((int)(UN), 1); dn += d * d;     \
        xa = __builtin_amdgcn_cvt_f32_fp8((int)(UA), 2);                      \
        d = xa - __builtin_amdgcn_cvt_f32_fp8((int)(UP), 2); dp += d * d;     \
        d = xa - __builtin_amdgcn_cvt_f32_fp8((int)(UN), 2); dn += d * d;     \
        xa = __builtin_amdgcn_cvt_f32_fp8((int)(UA), 3);                      \
        d = xa - __builtin_amdgcn_cvt_f32_fp8((int)(UP), 3); dp += d * d;     \
        d = xa - __builtin_amdgcn_cvt_f32_fp8((int)(UN), 3); dn += d * d;     \
    }

__global__ __launch_bounds__(256) void loss_k(
        const unsigned int* __restrict__ S8,
        const int* __restrict__ pos_idx,
        const int* __restrict__ neg_idx,
        const unsigned int* __restrict__ hp,
        const unsigned int* __restrict__ hn,
        float* __restrict__ partials) {
    __shared__ float sm[16];
    const int tid    = threadIdx.x;
    const int lane15 = tid & 15;
    const int grp    = tid >> 4;               // 0..15
    const char* S8B  = (const char*)S8;
    float lsum = 0.f;
#pragma unroll
    for (int c = 0; c < 4; ++c) {
        const int a = ((int)blockIdx.x * 4 + c) * 16 + grp;   // 0..40959
        const int k = a >> 11;
        const int i = a & 2047;
        const int* pidx = pos_idx + (k << 11);
        const int* nidx = neg_idx + (k << 11);
        const unsigned int kp = hp[a], kn = hn[a];
        const int jp = (int)((kp & 0x80000000u) ? (kp & 2047u) : ((~kp) & 2047u));
        const int jn = (int)((kn & 0x80000000u) ? (kn & 2047u) : ((~kn) & 2047u));
        const int ga = pidx[i];
        const int gp = pidx[jp];
        const int gn = nidx[jn];

        const uint4 va = *(const uint4*)(S8B + ((size_t)(uint32_t)ga << 8) + lane15 * 16);
        const uint4 vp = *(const uint4*)(S8B + ((size_t)(uint32_t)gp << 8) + lane15 * 16);
        const uint4 vn = *(const uint4*)(S8B + ((size_t)(uint32_t)gn << 8) + lane15 * 16);

        float dp = 0.f, dn = 0.f;
        ACC16(va.x, vp.x, vn.x)
        ACC16(va.y, vp.y, vn.y)
        ACC16(va.z, vp.z, vn.z)
        ACC16(va.w, vp.w, vn.w)

#pragma unroll
        for (int off = 1; off < 16; off <<= 1) {
            dp += __shfl_xor(dp, off);
            dn += __shfl_xor(dn, off);
        }
        if (lane15 == 0) {
            const float d_p = sqrtf(fmaxf(dp, 0.f) + EPS_D);
            const float d_n = sqrtf(fmaxf(dn, 0.f) + EPS_D);
            lsum += fmaxf(MARGIN_F + d_p - d_n, 0.f);
        }
    }
    if (lane15 == 0) sm[grp] = lsum;
    __syncthreads();
    if (tid == 0) {
        float s = 0.f;
#pragma unroll
        for (int g = 0; g < 16; ++g) s += sm[g];
        partials[blockIdx.x] = s;
    }
}

// ---------------- Kernel 4: tiny final reduction (640 partials) -------------
__global__ __launch_bounds__(64) void reduce_k(
        const float* __restrict__ partials, float* __restrict__ out) {
    const int tid = threadIdx.x;
    float s = 0.f;
    for (int i = tid; i < 640; i += 64) s += partials[i];
#pragma unroll
    for (int off = 32; off; off >>= 1) s += __shfl_down(s, off);
    if (tid == 0) out[0] = s * (1.0f / (float)P_POS);
}

extern "C" void kernel_launch(void* const* d_in, const int* in_sizes, int n_in,
                              void* d_out, int out_size, void* d_ws, size_t ws_size,
                              hipStream_t stream) {
    const float* feat    = (const float*)d_in[0];
    const int*   pos_idx = (const int*)d_in[1];
    const int*   neg_idx = (const int*)d_in[2];

    char* ws = (char*)d_ws;
    unsigned int* S8 = (unsigned int*)ws;                     // 16 MiB fp8 table
    float*        xx = (float*)(ws + 16777216);               // 256 KiB norms
    unsigned int* hp = (unsigned int*)(ws + 17039360);        // 160 KiB keys
    unsigned int* hn = (unsigned int*)(ws + 17203200);        // 160 KiB keys
    float*  partials = (float*)(ws + 17367040);               // 2.5 KiB

    sigmoid_norm_k<<<2048, 256, 0, stream>>>(feat, S8, xx, hp, hn);

    neg_select_k<<<640, 256, 0, stream>>>(S8, xx, pos_idx, neg_idx, hn);

    pos_select_k<<<720, 256, 0, stream>>>(S8, xx, pos_idx, hp);

    loss_k<<<640, 256, 0, stream>>>(S8, pos_idx, neg_idx, hp, hn, partials);

    reduce_k<<<1, 64, 0, stream>>>(partials, (float*)d_out);
}